// Round 7
// baseline (260.411 us; speedup 1.0000x reference)
//
#include <hip/hip_runtime.h>
#include <hip/hip_bf16.h>
#include <math.h>

#define B_ 64
#define L_ 2048
#define V_ 50000
#define E_ 300
#define H_ 128
#define C_ 10
#define TK 19              // k-tiles of 16 (K padded 300 -> 304)
#define NGB 782            // 64-row tiles

// ws layout (bytes):
//     0: mm[2] (encoded min/max)      8: cnt[2] (done counters)
//    16: bitmap[1563] (6252 B)
//  8192: cArr[2048] f32   16384: pArr[2048] f32   24576: SArr[128] f32
// 65536: embW1 bf16 [50000][128] (12.8 MB)
// 12865536: psum f32 [64][64][128] (2 MB)
// 14962688: wmax f32 [64][4][128] (128 KB)

typedef short bf16x8 __attribute__((ext_vector_type(8)));
typedef float f32x16 __attribute__((ext_vector_type(16)));

__device__ __forceinline__ unsigned enc_f32(float f) {
  unsigned u = __float_as_uint(f);
  return (u & 0x80000000u) ? ~u : (u | 0x80000000u);
}
__device__ __forceinline__ float dec_f32(unsigned u) {
  unsigned v = (u & 0x80000000u) ? (u ^ 0x80000000u) : ~u;
  return __uint_as_float(v);
}
__device__ __forceinline__ unsigned short f2bf(float f) {  // RNE f32->bf16
  unsigned u = __float_as_uint(f);
  unsigned r = 0x7FFFu + ((u >> 16) & 1u);
  return (unsigned short)((u + r) >> 16);
}

// ---- K0: init mm + counters + zero bitmap ----
__global__ __launch_bounds__(512) void k_init(unsigned* __restrict__ mm,
                                              unsigned* __restrict__ cnt,
                                              unsigned* __restrict__ bm) {
  const int t = threadIdx.x;
  if (t == 0) { mm[0] = 0xFFFFFFFFu; mm[1] = 0u; cnt[0] = 0u; cnt[1] = 0u; }
  for (int i = t; i < 1563; i += 512) bm[i] = 0u;
}

// ---- K1: presence bitmap ----
__global__ __launch_bounds__(256) void k_bitmap(const int* __restrict__ x,
                                                unsigned* __restrict__ bm) {
  const int i = blockIdx.x * 256 + threadIdx.x;
  const int v = x[i];
  atomicOr(&bm[v >> 5], 1u << (v & 31));
}

// ---- K2: embW1 = bf16(emb @ W1), no LDS / no barriers in the hot path.
// 4 waves/block; wave w owns 32 H-cols; streams 2 row-tiles of 32 emb rows
// global->reg->cvt->mfma_32x32x16 with 3-deep prefetch. Wave 0 also does the
// presence-filtered min/max. Last-finishing block runs the Newton scan. ----
__global__ __launch_bounds__(256, 3) void k_gemm(
    const float* __restrict__ emb, const float* __restrict__ W1,
    const unsigned* __restrict__ bm, unsigned* __restrict__ mm,
    unsigned short* __restrict__ embW1, unsigned* __restrict__ cnt,
    const float* __restrict__ alphaP, const float* __restrict__ betaP,
    float* __restrict__ cArr, float* __restrict__ pArr,
    float* __restrict__ SArr) {
  __shared__ bool lastf;
  const int bid = blockIdx.x;
  const int tid = threadIdx.x;
  const int wv = tid >> 6, lane = tid & 63;
  const int l31 = lane & 31, hi = lane >> 5;
  const int col = wv * 32 + l31;
  const int r0 = bid * 64;

  // B-fragments: W1 (k x n), n = col, k = kt*16 + hi*8 + i
  bf16x8 bfr[TK];
#pragma unroll
  for (int kt = 0; kt < TK; ++kt) {
#pragma unroll
    for (int i = 0; i < 8; ++i) {
      const int k = kt * 16 + hi * 8 + i;
      bfr[kt][i] = (short)((k < E_) ? f2bf(W1[k * H_ + col]) : 0);
    }
  }

  float mn = 3.4e38f, mx = -3.4e38f;

#pragma unroll
  for (int rt = 0; rt < 2; ++rt) {
    const int rr0 = r0 + rt * 32;
    const int row = rr0 + l31;                    // this lane's emb row (A m-dim)
    const float* rp = emb + (size_t)((row < V_) ? row : (V_ - 1)) * E_;
    const bool pres = (wv == 0) && (row < V_) && ((bm[row >> 5] >> (row & 31)) & 1u);
    f32x16 acc = {0,0,0,0,0,0,0,0,0,0,0,0,0,0,0,0};
    float4 pf[3][2];
#pragma unroll
    for (int p = 0; p < 3; ++p) {                 // prologue kt=0..2 (k<=47, safe)
      const int k0 = p * 16 + hi * 8;
      pf[p][0] = *(const float4*)(rp + k0);
      pf[p][1] = *(const float4*)(rp + k0 + 4);
    }
#pragma unroll
    for (int kt = 0; kt < TK; ++kt) {
      const float4 lo = pf[kt % 3][0], hi4 = pf[kt % 3][1];
      if (kt + 3 < TK) {                          // prefetch kt+3
        const int k0 = (kt + 3) * 16 + hi * 8;
        pf[kt % 3][0] = *(const float4*)(rp + k0);
        pf[kt % 3][1] = (kt + 3 == TK - 1 && hi == 1) ? float4{0, 0, 0, 0}
                                                      : *(const float4*)(rp + k0 + 4);
      }
      const float va[8] = {lo.x, lo.y, lo.z, lo.w, hi4.x, hi4.y, hi4.z, hi4.w};
      bf16x8 af;
#pragma unroll
      for (int i = 0; i < 8; ++i) {
        const int k = kt * 16 + hi * 8 + i;
        float v = (k < E_) ? va[i] : 0.0f;
        if (pres && k < E_) { mn = fminf(mn, v); mx = fmaxf(mx, v); }
        af[i] = (short)f2bf(v);
      }
      acc = __builtin_amdgcn_mfma_f32_32x32x16_bf16(af, bfr[kt], acc, 0, 0, 0);
    }
    // D: col = lane&31 (H col), row m = (r&3)+8*(r>>2)+4*hi (emb row offset)
#pragma unroll
    for (int r = 0; r < 16; ++r) {
      const int erow = rr0 + (r & 3) + 8 * (r >> 2) + 4 * hi;
      if (erow < V_) embW1[(size_t)erow * H_ + col] = f2bf(acc[r]);
    }
  }

  // ---- wave-0 min/max -> atomics; done-counter; last block runs scan ----
  if (wv == 0) {
#pragma unroll
    for (int s = 1; s < 64; s <<= 1) {
      mn = fminf(mn, __shfl_xor(mn, s));
      mx = fmaxf(mx, __shfl_xor(mx, s));
    }
    if (lane == 0) {
      atomicMin(&mm[0], enc_f32(mn));
      atomicMax(&mm[1], enc_f32(mx));
      __threadfence();
      lastf = (atomicAdd(&cnt[0], 1u) == NGB - 1u);
    }
  }
  __syncthreads();
  if (!lastf) return;

  // ===== fused Newton scan for c_t, P_t (tid<64) + SArr (tid 64..191) =====
  if (tid < 64) {
    const int ln = tid;
    const float alpha = alphaP[0];
    const float lmn = dec_f32(atomicOr(&mm[0], 0u));
    const float lmx = dec_f32(atomicOr(&mm[1], 0u));
    const float sb = betaP[0] * lmn / (lmx - lmn);   // -beta*xn(xe=0)
    const float tl = (float)(ln * 32);

    float c = sqrtf(fmaf(2.0f * alpha, tl, 1.0f));
    if (fabsf(sb) > 1e-7f) {
      const float isb = 1.0f / sb;
      const float k2 = alpha * isb * isb;
      const float d0 = fmaxf(alpha + sb, 1e-8f);
#pragma unroll
      for (int it = 0; it < 4; ++it) {
        const float den = fmaxf(fmaf(sb, c, alpha), 1e-8f);
        const float T = (c - 1.0f) * isb - k2 * logf(den / d0);
        c = c - (T - tl) * den / c;
        c = fminf(fmaxf(c, 1.0f), 1e3f);
      }
    }
    if (ln == 0) c = 1.0f;

#pragma unroll
    for (int sw = 0; sw < 3; ++sw) {
      float cc = c, d = 1.0f;
#pragma unroll
      for (int j = 0; j < 32; ++j) {
        const float r = __builtin_amdgcn_rcpf(cc);
        d *= fmaf(-alpha * r, r, 1.0f);
        cc = fmaf(alpha, r, cc) + sb;
      }
      float A = d, Bv = fmaf(-d, c, cc);
#pragma unroll
      for (int o = 1; o < 64; o <<= 1) {
        const float A2 = __shfl_up(A, o);
        const float B2 = __shfl_up(Bv, o);
        if (ln >= o) { Bv = fmaf(A, B2, Bv); A *= A2; }
      }
      const float As = __shfl_up(A, 1);
      const float Bs = __shfl_up(Bv, 1);
      if (ln > 0) c = As + Bs;
    }

    float av[32];
    float cc = c, Q = 1.0f;
#pragma unroll
    for (int j = 0; j < 32; ++j) {
      cArr[ln * 32 + j] = cc;
      const float r = __builtin_amdgcn_rcpf(cc);
      const float a = fmaf(-alpha * r, r, 1.0f);
      av[j] = a; Q *= a;
      cc = fmaf(alpha, r, cc) + sb;
    }
    float Pp = Q;
#pragma unroll
    for (int o = 1; o < 64; o <<= 1) {
      const float q2 = __shfl_up(Pp, o);
      if (ln >= o) Pp *= q2;
    }
    const float Ps = __shfl_up(Pp, 1);
    float P = (ln == 0) ? 1.0f : Ps;
#pragma unroll
    for (int j = 0; j < 32; ++j) {
      pArr[ln * 32 + j] = P;
      P *= av[j];
    }
  } else if (tid < 192) {
    const int cl = tid - 64;
    float s = 0.0f;
    for (int k = 0; k < E_; ++k) s += W1[k * H_ + cl];
    SArr[cl] = s;
  }
}

// ---- K3: per-(b, 32-step segment) partial sums of q_s * y_s ----
__global__ __launch_bounds__(256) void k_psum(const int* __restrict__ x,
                                              const unsigned short* __restrict__ embW1,
                                              const float* __restrict__ pArr,
                                              float* __restrict__ psum) {
  const int bid = blockIdx.x;             // 1024 blocks
  const int b = bid >> 4, sq = bid & 15;
  const int wv = threadIdx.x >> 6, lane = threadIdx.x & 63;
  const int v = sq * 4 + wv;              // 0..63
  const int t0 = v * 32;
  const int col2 = lane * 2;
  float s0 = 0.f, s1 = 0.f;
#pragma unroll 8
  for (int j = 0; j < 32; ++j) {
    const int t = t0 + j;
    const int tok = x[b * L_ + t];
    const float q = (t + 1 < L_) ? __builtin_amdgcn_rcpf(pArr[t + 1]) : 0.0f;
    const unsigned y2 = *(const unsigned*)(embW1 + (size_t)tok * H_ + col2);
    s0 = fmaf(q, __uint_as_float(y2 << 16), s0);
    s1 = fmaf(q, __uint_as_float(y2 & 0xFFFF0000u), s1);
  }
  float* p = psum + (size_t)(b * 64 + v) * H_ + col2;
  p[0] = s0; p[1] = s1;
}

// ---- K4: z-max per (b, quarter); last block fuses tanh + W2 matvec ----
__global__ __launch_bounds__(1024) void k_zmax(
    const int* __restrict__ x, const unsigned short* __restrict__ embW1,
    const float* __restrict__ cArr, const float* __restrict__ pArr,
    const float* __restrict__ SArr, const float* __restrict__ psum,
    const float* __restrict__ betaP, const unsigned* __restrict__ mm,
    float* __restrict__ wmax, unsigned* __restrict__ cnt,
    const float* __restrict__ b1, const float* __restrict__ W2,
    const float* __restrict__ b2, float* __restrict__ out) {
  __shared__ float zsh[16][128];
  __shared__ float psh[64][128];
  __shared__ bool lastf;
  const int bid = blockIdx.x;             // 256 blocks
  const int b = bid >> 2, qt = bid & 3;
  const int wv = threadIdx.x >> 6, lane = threadIdx.x & 63;
  const int v = qt * 16 + wv;             // 0..63
  const int t0 = v * 32;
  const int col2 = lane * 2;
  const float mn = dec_f32(mm[0]), mx = dec_f32(mm[1]);
  const float binv = betaP[0] / (mx - mn);
  const float S0 = SArr[col2], S1 = SArr[col2 + 1];

  float m0 = 0.f, m1 = 0.f;               // prefix m at t0 from psum
  for (int u = 0; u < v; ++u) {
    const float* p = psum + (size_t)(b * 64 + u) * H_ + col2;
    m0 += p[0]; m1 += p[1];
  }
  float z0m = -3.4e38f, z1m = -3.4e38f;
#pragma unroll 4
  for (int j = 0; j < 32; ++j) {
    const int t = t0 + j;
    const int tok = x[b * L_ + t];
    const unsigned y2 = *(const unsigned*)(embW1 + (size_t)tok * H_ + col2);
    const float ct = cArr[t];
    const float gt = binv * pArr[t];
    const float q = (t + 1 < L_) ? __builtin_amdgcn_rcpf(pArr[t + 1]) : 0.0f;
    z0m = fmaxf(z0m, fmaf(-gt, m0, ct * S0));   // z uses m BEFORE adding term t
    z1m = fmaxf(z1m, fmaf(-gt, m1, ct * S1));
    m0 = fmaf(q, __uint_as_float(y2 << 16), m0);
    m1 = fmaf(q, __uint_as_float(y2 & 0xFFFF0000u), m1);
  }
  zsh[wv][col2] = z0m; zsh[wv][col2 + 1] = z1m;
  __syncthreads();
  if (threadIdx.x < 128) {
    float mz = zsh[0][threadIdx.x];
#pragma unroll
    for (int w2 = 1; w2 < 16; ++w2) mz = fmaxf(mz, zsh[w2][threadIdx.x]);
    wmax[(b * 4 + qt) * H_ + threadIdx.x] = mz;
    __threadfence();
  }
  __syncthreads();
  if (threadIdx.x == 0) lastf = (atomicAdd(&cnt[1], 1u) == 255u);
  __syncthreads();
  if (!lastf) return;

  // ===== fused tail: pooled = tanh(max_q wmax + b1); out = pooled@W2 + b2 =====
  __threadfence();
  for (int idx = threadIdx.x; idx < B_ * H_; idx += 1024) {
    const int bb = idx >> 7, h = idx & 127;
    float mz = wmax[(bb * 4) * H_ + h];
#pragma unroll
    for (int q2 = 1; q2 < 4; ++q2) mz = fmaxf(mz, wmax[(bb * 4 + q2) * H_ + h]);
    psh[bb][h] = tanhf(mz + b1[h]);
  }
  __syncthreads();
  if (threadIdx.x < B_ * C_) {
    const int bb = threadIdx.x / C_, c = threadIdx.x % C_;
    float s = b2[c];
#pragma unroll 8
    for (int k = 0; k < H_; ++k) s = fmaf(psh[bb][k], W2[k * C_ + c], s);
    out[threadIdx.x] = s;
  }
}

extern "C" void kernel_launch(void* const* d_in, const int* in_sizes, int n_in,
                              void* d_out, int out_size, void* d_ws, size_t ws_size,
                              hipStream_t stream) {
  const int* x = (const int*)d_in[0];
  const float* emb = (const float*)d_in[1];
  const float* alpha = (const float*)d_in[2];
  const float* beta = (const float*)d_in[3];
  const float* W1 = (const float*)d_in[4];
  const float* b1 = (const float*)d_in[5];
  const float* W2 = (const float*)d_in[6];
  const float* b2 = (const float*)d_in[7];
  (void)in_sizes; (void)n_in; (void)out_size; (void)ws_size;

  char* ws = (char*)d_ws;
  unsigned* mm = (unsigned*)ws;
  unsigned* cnt = (unsigned*)(ws + 8);
  unsigned* bm = (unsigned*)(ws + 16);
  float* cArr = (float*)(ws + 8192);
  float* pArr = (float*)(ws + 16384);
  float* SArr = (float*)(ws + 24576);
  unsigned short* embW1 = (unsigned short*)(ws + 65536);
  float* psum = (float*)(ws + 12865536);
  float* wmax = (float*)(ws + 14962688);

  k_init<<<1, 512, 0, stream>>>(mm, cnt, bm);
  k_bitmap<<<(B_ * L_) / 256, 256, 0, stream>>>(x, bm);
  k_gemm<<<NGB, 256, 0, stream>>>(emb, W1, bm, mm, embW1, cnt,
                                  alpha, beta, cArr, pArr, SArr);
  k_psum<<<1024, 256, 0, stream>>>(x, embW1, pArr, psum);
  k_zmax<<<256, 1024, 0, stream>>>(x, embW1, cArr, pArr, SArr, psum, beta, mm,
                                   wmax, cnt, b1, W2, b2, (float*)d_out);
}

// Round 8
// 163.345 us; speedup vs baseline: 1.5942x; 1.5942x over previous
//
#include <hip/hip_runtime.h>
#include <hip/hip_bf16.h>
#include <math.h>

#define B_ 64
#define L_ 2048
#define V_ 50000
#define E_ 300
#define H_ 128
#define C_ 10
#define NGB2 391           // 128-row tiles
#define RST 308            // LDS row stride in f32 (1232 B; 2-way-bank-free)
#define SUBF 5120          // f32 per subtile buffer (20480 B = 1280 x 16B chunks)

// ws layout (bytes):
//     0: mm[2] (encoded min/max)      8: cnt[2] (done counters)
//    16: bitmap[1563] (6252 B)
//  8192: cArr[2048] f32   16384: pArr[2048] f32   24576: SArr[128] f32
// 65536: embW1 bf16 [50000][128] (12.8 MB)
// 12865536: psum f32 [64][64][128] (2 MB)
// 14962688: wmax f32 [64][4][128] (128 KB)

typedef short bf16x8 __attribute__((ext_vector_type(8)));
typedef float f32x4 __attribute__((ext_vector_type(4)));

__device__ __forceinline__ unsigned enc_f32(float f) {
  unsigned u = __float_as_uint(f);
  return (u & 0x80000000u) ? ~u : (u | 0x80000000u);
}
__device__ __forceinline__ float dec_f32(unsigned u) {
  unsigned v = (u & 0x80000000u) ? (u ^ 0x80000000u) : ~u;
  return __uint_as_float(v);
}
__device__ __forceinline__ unsigned short f2bf(float f) {  // RNE f32->bf16
  unsigned u = __float_as_uint(f);
  unsigned r = 0x7FFFu + ((u >> 16) & 1u);
  return (unsigned short)((u + r) >> 16);
}
__device__ __forceinline__ void gload16(const float* g, float* l) {
  __builtin_amdgcn_global_load_lds(
      (const __attribute__((address_space(1))) void*)g,
      (__attribute__((address_space(3))) void*)l, 16, 0, 0);
}

// ---- K0: init mm + counters + zero bitmap ----
__global__ __launch_bounds__(512) void k_init(unsigned* __restrict__ mm,
                                              unsigned* __restrict__ cnt,
                                              unsigned* __restrict__ bm) {
  const int t = threadIdx.x;
  if (t == 0) { mm[0] = 0xFFFFFFFFu; mm[1] = 0u; cnt[0] = 0u; cnt[1] = 0u; }
  for (int i = t; i < 1563; i += 512) bm[i] = 0u;
}

// ---- K1: presence bitmap ----
__global__ __launch_bounds__(256) void k_bitmap(const int* __restrict__ x,
                                                unsigned* __restrict__ bm) {
  const int i = blockIdx.x * 256 + threadIdx.x;
  const int v = x[i];
  atomicOr(&bm[v >> 5], 1u << (v & 31));
}

// ---- K2: embW1 = bf16(emb @ W1) via global_load_lds f32 staging.
// 391 blocks x 512 thr; 128 rows/block as 8 double-buffered 16-row subtiles.
// Wave 0's fragment pass also does the once-per-element presence min/max.
// Last-finishing block runs the parallel Newton scan (c_t, P_t) + SArr. ----
__global__ __launch_bounds__(512) void k_gemm(
    const float* __restrict__ emb, const float* __restrict__ W1,
    const unsigned* __restrict__ bm, unsigned* __restrict__ mm,
    unsigned short* __restrict__ embW1, unsigned* __restrict__ cnt,
    const float* __restrict__ alphaP, const float* __restrict__ betaP,
    float* __restrict__ cArr, float* __restrict__ pArr,
    float* __restrict__ SArr) {
  __shared__ float lds[2][SUBF];
  __shared__ bool lastf;
  const int bid = blockIdx.x;
  const int tid = threadIdx.x;
  const int wv = tid >> 6, lane = tid & 63;
  const int arow = lane & 15, g = lane >> 4;
  const int r0 = bid * 128;

  // A-fragments: W1 (m = H col, k = kt*32 + g*8 + i), resident all kernel
  bf16x8 bfr[10];
  const int col = wv * 16 + arow;
#pragma unroll
  for (int kt = 0; kt < 10; ++kt) {
#pragma unroll
    for (int i = 0; i < 8; ++i) {
      const int k = kt * 32 + g * 8 + i;
      bfr[kt][i] = (short)((k < E_) ? f2bf(W1[k * H_ + col]) : 0);
    }
  }

  // stage subtile s: 1232 chunks of 16 B, linear LDS fill, 20 wave-calls
  auto stage = [&](int s) {
    const int rbase = r0 + s * 16;
    float* dst = lds[s & 1];
    for (int i = wv; i < 20; i += 8) {
      const int h = i * 64 + lane;          // chunk index (<=1279)
      int r = h / 77;
      const int c16 = h - r * 77;
      if (r > 15) r = 15;                   // tail-call clamp (slack region)
      int row = rbase + r;
      if (row >= V_) row = V_ - 1;
      const int cc = (c16 < 75) ? c16 * 4 : 0;   // pad chunks read row start
      gload16(emb + (size_t)row * E_ + cc, dst + h * 4);
    }
  };

  stage(0);
  stage(1);

  float mn = 3.4e38f, mx = -3.4e38f;

  for (int s = 0; s < 8; ++s) {
    __syncthreads();                         // subtile s resident (vmcnt drain)
    const float* bp = lds[s & 1];
    const int prow = r0 + s * 16 + arow;
    const bool pres = (wv == 0) && (prow < V_) &&
                      ((bm[prow >> 5] >> (prow & 31)) & 1u);
    f32x4 acc = {0, 0, 0, 0};
#pragma unroll
    for (int kt = 0; kt < 10; ++kt) {
      const float* ep = bp + arow * RST + kt * 32 + g * 8;
      const float4 lo = *(const float4*)(ep);
      const float4 h4 = *(const float4*)(ep + 4);
      const float vv[8] = {lo.x, lo.y, lo.z, lo.w, h4.x, h4.y, h4.z, h4.w};
      bf16x8 bb;
#pragma unroll
      for (int j = 0; j < 8; ++j) {
        bb[j] = (short)f2bf(vv[j]);
        if (pres && (kt * 32 + g * 8 + j) < E_) {
          mn = fminf(mn, vv[j]);
          mx = fmaxf(mx, vv[j]);
        }
      }
      acc = __builtin_amdgcn_mfma_f32_16x16x32_bf16(bfr[kt], bb, acc, 0, 0, 0);
    }
    // D: n(=lane&15) = emb row offset, m(=g*4+i) = H col offset
    const int erow = r0 + s * 16 + arow;
    if (erow < V_) {
      unsigned long long p = (unsigned long long)f2bf(acc[0])
                           | ((unsigned long long)f2bf(acc[1]) << 16)
                           | ((unsigned long long)f2bf(acc[2]) << 32)
                           | ((unsigned long long)f2bf(acc[3]) << 48);
      *(unsigned long long*)&embW1[(size_t)erow * H_ + wv * 16 + g * 4] = p;
    }
    __syncthreads();                         // all reads of buf done
    if (s + 2 < 8) stage(s + 2);             // refill the freed buffer
  }

  // ---- wave-0 min/max -> atomics; done-counter; last block runs scan ----
  if (wv == 0) {
#pragma unroll
    for (int s = 1; s < 64; s <<= 1) {
      mn = fminf(mn, __shfl_xor(mn, s));
      mx = fmaxf(mx, __shfl_xor(mx, s));
    }
    if (lane == 0) {
      atomicMin(&mm[0], enc_f32(mn));
      atomicMax(&mm[1], enc_f32(mx));
      __threadfence();
      lastf = (atomicAdd(&cnt[0], 1u) == NGB2 - 1u);
    }
  }
  __syncthreads();
  if (!lastf) return;

  // ===== fused Newton scan for c_t, P_t (tid<64) + SArr (tid 64..191) =====
  if (tid < 64) {
    const int ln = tid;
    const float alpha = alphaP[0];
    const float lmn = dec_f32(atomicOr(&mm[0], 0u));
    const float lmx = dec_f32(atomicOr(&mm[1], 0u));
    const float sb = betaP[0] * lmn / (lmx - lmn);   // -beta*xn(xe=0)
    const float tl = (float)(ln * 32);

    float c = sqrtf(fmaf(2.0f * alpha, tl, 1.0f));
    if (fabsf(sb) > 1e-7f) {
      const float isb = 1.0f / sb;
      const float k2 = alpha * isb * isb;
      const float d0 = fmaxf(alpha + sb, 1e-8f);
#pragma unroll
      for (int it = 0; it < 4; ++it) {
        const float den = fmaxf(fmaf(sb, c, alpha), 1e-8f);
        const float T = (c - 1.0f) * isb - k2 * logf(den / d0);
        c = c - (T - tl) * den / c;
        c = fminf(fmaxf(c, 1.0f), 1e3f);
      }
    }
    if (ln == 0) c = 1.0f;

#pragma unroll
    for (int sw = 0; sw < 3; ++sw) {
      float cc = c, d = 1.0f;
#pragma unroll
      for (int j = 0; j < 32; ++j) {
        const float r = __builtin_amdgcn_rcpf(cc);
        d *= fmaf(-alpha * r, r, 1.0f);
        cc = fmaf(alpha, r, cc) + sb;
      }
      float A = d, Bv = fmaf(-d, c, cc);
#pragma unroll
      for (int o = 1; o < 64; o <<= 1) {
        const float A2 = __shfl_up(A, o);
        const float B2 = __shfl_up(Bv, o);
        if (ln >= o) { Bv = fmaf(A, B2, Bv); A *= A2; }
      }
      const float As = __shfl_up(A, 1);
      const float Bs = __shfl_up(Bv, 1);
      if (ln > 0) c = As + Bs;
    }

    float av[32];
    float cc = c, Q = 1.0f;
#pragma unroll
    for (int j = 0; j < 32; ++j) {
      cArr[ln * 32 + j] = cc;
      const float r = __builtin_amdgcn_rcpf(cc);
      const float a = fmaf(-alpha * r, r, 1.0f);
      av[j] = a; Q *= a;
      cc = fmaf(alpha, r, cc) + sb;
    }
    float Pp = Q;
#pragma unroll
    for (int o = 1; o < 64; o <<= 1) {
      const float q2 = __shfl_up(Pp, o);
      if (ln >= o) Pp *= q2;
    }
    const float Ps = __shfl_up(Pp, 1);
    float P = (ln == 0) ? 1.0f : Ps;
#pragma unroll
    for (int j = 0; j < 32; ++j) {
      pArr[ln * 32 + j] = P;
      P *= av[j];
    }
  } else if (tid < 192) {
    const int cl = tid - 64;
    float s = 0.0f;
    for (int k = 0; k < E_; ++k) s += W1[k * H_ + cl];
    SArr[cl] = s;
  }
}

// ---- K3: per-(b, 32-step segment) partial sums of q_s * y_s ----
__global__ __launch_bounds__(256) void k_psum(const int* __restrict__ x,
                                              const unsigned short* __restrict__ embW1,
                                              const float* __restrict__ pArr,
                                              float* __restrict__ psum) {
  const int bid = blockIdx.x;             // 1024 blocks
  const int b = bid >> 4, sq = bid & 15;
  const int wv = threadIdx.x >> 6, lane = threadIdx.x & 63;
  const int v = sq * 4 + wv;              // 0..63
  const int t0 = v * 32;
  const int col2 = lane * 2;
  float s0 = 0.f, s1 = 0.f;
#pragma unroll 8
  for (int j = 0; j < 32; ++j) {
    const int t = t0 + j;
    const int tok = x[b * L_ + t];
    const float q = (t + 1 < L_) ? __builtin_amdgcn_rcpf(pArr[t + 1]) : 0.0f;
    const unsigned y2 = *(const unsigned*)(embW1 + (size_t)tok * H_ + col2);
    s0 = fmaf(q, __uint_as_float(y2 << 16), s0);
    s1 = fmaf(q, __uint_as_float(y2 & 0xFFFF0000u), s1);
  }
  float* p = psum + (size_t)(b * 64 + v) * H_ + col2;
  p[0] = s0; p[1] = s1;
}

// ---- K4: z-max per (b, quarter); last block fuses tanh + W2 matvec ----
__global__ __launch_bounds__(1024) void k_zmax(
    const int* __restrict__ x, const unsigned short* __restrict__ embW1,
    const float* __restrict__ cArr, const float* __restrict__ pArr,
    const float* __restrict__ SArr, const float* __restrict__ psum,
    const float* __restrict__ betaP, const unsigned* __restrict__ mm,
    float* __restrict__ wmax, unsigned* __restrict__ cnt,
    const float* __restrict__ b1, const float* __restrict__ W2,
    const float* __restrict__ b2, float* __restrict__ out) {
  __shared__ float zsh[16][128];
  __shared__ float psh[64][128];
  __shared__ bool lastf;
  const int bid = blockIdx.x;             // 256 blocks
  const int b = bid >> 2, qt = bid & 3;
  const int wv = threadIdx.x >> 6, lane = threadIdx.x & 63;
  const int v = qt * 16 + wv;             // 0..63
  const int t0 = v * 32;
  const int col2 = lane * 2;
  const float mn = dec_f32(mm[0]), mx = dec_f32(mm[1]);
  const float binv = betaP[0] / (mx - mn);
  const float S0 = SArr[col2], S1 = SArr[col2 + 1];

  float m0 = 0.f, m1 = 0.f;               // prefix m at t0 from psum
  for (int u = 0; u < v; ++u) {
    const float* p = psum + (size_t)(b * 64 + u) * H_ + col2;
    m0 += p[0]; m1 += p[1];
  }
  float z0m = -3.4e38f, z1m = -3.4e38f;
#pragma unroll 4
  for (int j = 0; j < 32; ++j) {
    const int t = t0 + j;
    const int tok = x[b * L_ + t];
    const unsigned y2 = *(const unsigned*)(embW1 + (size_t)tok * H_ + col2);
    const float ct = cArr[t];
    const float gt = binv * pArr[t];
    const float q = (t + 1 < L_) ? __builtin_amdgcn_rcpf(pArr[t + 1]) : 0.0f;
    z0m = fmaxf(z0m, fmaf(-gt, m0, ct * S0));   // z uses m BEFORE adding term t
    z1m = fmaxf(z1m, fmaf(-gt, m1, ct * S1));
    m0 = fmaf(q, __uint_as_float(y2 << 16), m0);
    m1 = fmaf(q, __uint_as_float(y2 & 0xFFFF0000u), m1);
  }
  zsh[wv][col2] = z0m; zsh[wv][col2 + 1] = z1m;
  __syncthreads();
  if (threadIdx.x < 128) {
    float mz = zsh[0][threadIdx.x];
#pragma unroll
    for (int w2 = 1; w2 < 16; ++w2) mz = fmaxf(mz, zsh[w2][threadIdx.x]);
    wmax[(b * 4 + qt) * H_ + threadIdx.x] = mz;
    __threadfence();
  }
  __syncthreads();
  if (threadIdx.x == 0) lastf = (atomicAdd(&cnt[1], 1u) == 255u);
  __syncthreads();
  if (!lastf) return;

  // ===== fused tail: pooled = tanh(max_q wmax + b1); out = pooled@W2 + b2 =====
  __threadfence();
  for (int idx = threadIdx.x; idx < B_ * H_; idx += 1024) {
    const int bb = idx >> 7, h = idx & 127;
    float mz = wmax[(bb * 4) * H_ + h];
#pragma unroll
    for (int q2 = 1; q2 < 4; ++q2) mz = fmaxf(mz, wmax[(bb * 4 + q2) * H_ + h]);
    psh[bb][h] = tanhf(mz + b1[h]);
  }
  __syncthreads();
  if (threadIdx.x < B_ * C_) {
    const int bb = threadIdx.x / C_, c = threadIdx.x % C_;
    float s = b2[c];
#pragma unroll 8
    for (int k = 0; k < H_; ++k) s = fmaf(psh[bb][k], W2[k * C_ + c], s);
    out[threadIdx.x] = s;
  }
}

extern "C" void kernel_launch(void* const* d_in, const int* in_sizes, int n_in,
                              void* d_out, int out_size, void* d_ws, size_t ws_size,
                              hipStream_t stream) {
  const int* x = (const int*)d_in[0];
  const float* emb = (const float*)d_in[1];
  const float* alpha = (const float*)d_in[2];
  const float* beta = (const float*)d_in[3];
  const float* W1 = (const float*)d_in[4];
  const float* b1 = (const float*)d_in[5];
  const float* W2 = (const float*)d_in[6];
  const float* b2 = (const float*)d_in[7];
  (void)in_sizes; (void)n_in; (void)out_size; (void)ws_size;

  char* ws = (char*)d_ws;
  unsigned* mm = (unsigned*)ws;
  unsigned* cnt = (unsigned*)(ws + 8);
  unsigned* bm = (unsigned*)(ws + 16);
  float* cArr = (float*)(ws + 8192);
  float* pArr = (float*)(ws + 16384);
  float* SArr = (float*)(ws + 24576);
  unsigned short* embW1 = (unsigned short*)(ws + 65536);
  float* psum = (float*)(ws + 12865536);
  float* wmax = (float*)(ws + 14962688);

  k_init<<<1, 512, 0, stream>>>(mm, cnt, bm);
  k_bitmap<<<(B_ * L_) / 256, 256, 0, stream>>>(x, bm);
  k_gemm<<<NGB2, 512, 0, stream>>>(emb, W1, bm, mm, embW1, cnt,
                                   alpha, beta, cArr, pArr, SArr);
  k_psum<<<1024, 256, 0, stream>>>(x, embW1, pArr, psum);
  k_zmax<<<256, 1024, 0, stream>>>(x, embW1, cArr, pArr, SArr, psum, beta, mm,
                                   wmax, cnt, b1, W2, b2, (float*)d_out);
}